// Round 1
// baseline (360.191 us; speedup 1.0000x reference)
//
#include <hip/hip_runtime.h>
#include <hip/hip_bf16.h>

namespace {

constexpr int E  = 64;
constexpr int C  = 64;
constexpr int D  = 1024;
constexpr int DF = 2048;
constexpr int BN = 128;   // N-tile per block
constexpr int BK = 32;    // K per step
constexpr int KPAD = 40;  // padded LDS row length in bf16 elems (80 B)

using u16    = unsigned short;
using f32x4  = __attribute__((ext_vector_type(4))) float;
using short8 = __attribute__((ext_vector_type(8))) short;
using float4v = __attribute__((ext_vector_type(4))) float;

__device__ __forceinline__ u16 f2bf(float f) {
  union { float f; unsigned u; } v;
  v.f = f;
  unsigned u = v.u;
  return (u16)((u + 0x7fffu + ((u >> 16) & 1u)) >> 16);  // RNE
}

// ---------------- Stage 1: hidden = silu(X*Wg^T) * (X*Wu^T), bf16 out ------
__global__ __launch_bounds__(256, 2) void ffn_stage1(
    const float* __restrict__ X, const float* __restrict__ Wg,
    const float* __restrict__ Wu, u16* __restrict__ H) {
  const int e   = blockIdx.y;
  const int n0  = blockIdx.x * BN;
  const int tid = threadIdx.x;
  const int lane = tid & 63;
  const int wv   = tid >> 6;

  __shared__ __align__(16) u16 lds[2][12800];  // X 64x40 | Wg 128x40 | Wu 128x40
  constexpr int OX = 0, OG = 2560, OU = 7680;

  const int xrow = tid >> 2, xs = (tid & 3) * 8;   // 8 f32 per thread for X
  const int wrow = tid >> 1, wh = (tid & 1) * 16;  // 16 f32 per thread per W

  const float* xp = X  + (size_t)(e * C + xrow) * D + xs;
  const float* gp = Wg + ((size_t)e * DF + n0 + wrow) * D + wh;
  const float* up = Wu + ((size_t)e * DF + n0 + wrow) * D + wh;

  float4v xv[2], gv[4], uv[4];

  auto LOAD = [&](int k0) {
    const float4v* x4 = reinterpret_cast<const float4v*>(xp + k0);
    xv[0] = x4[0]; xv[1] = x4[1];
    const float4v* g4 = reinterpret_cast<const float4v*>(gp + k0);
    gv[0] = g4[0]; gv[1] = g4[1]; gv[2] = g4[2]; gv[3] = g4[3];
    const float4v* u4 = reinterpret_cast<const float4v*>(up + k0);
    uv[0] = u4[0]; uv[1] = u4[1]; uv[2] = u4[2]; uv[3] = u4[3];
  };

  auto STORE = [&](u16* buf) {
    short8 xb;
#pragma unroll
    for (int i = 0; i < 4; ++i) {
      xb[i] = (short)f2bf(xv[0][i]); xb[4 + i] = (short)f2bf(xv[1][i]);
    }
    *reinterpret_cast<short8*>(&buf[OX + xrow * KPAD + xs]) = xb;
    short8 g0, g1, u0, u1;
#pragma unroll
    for (int i = 0; i < 4; ++i) {
      g0[i] = (short)f2bf(gv[0][i]); g0[4 + i] = (short)f2bf(gv[1][i]);
      g1[i] = (short)f2bf(gv[2][i]); g1[4 + i] = (short)f2bf(gv[3][i]);
      u0[i] = (short)f2bf(uv[0][i]); u0[4 + i] = (short)f2bf(uv[1][i]);
      u1[i] = (short)f2bf(uv[2][i]); u1[4 + i] = (short)f2bf(uv[3][i]);
    }
    u16* wb = &buf[OG + wrow * KPAD + wh];
    *reinterpret_cast<short8*>(wb)     = g0;
    *reinterpret_cast<short8*>(wb + 8) = g1;
    u16* ub = &buf[OU + wrow * KPAD + wh];
    *reinterpret_cast<short8*>(ub)     = u0;
    *reinterpret_cast<short8*>(ub + 8) = u1;
  };

  const f32x4 zero = {0.f, 0.f, 0.f, 0.f};
  f32x4 accg[4][2], accu[4][2];
#pragma unroll
  for (int mf = 0; mf < 4; ++mf)
#pragma unroll
    for (int nf = 0; nf < 2; ++nf) { accg[mf][nf] = zero; accu[mf][nf] = zero; }

  LOAD(0);
  STORE(lds[0]);
  __syncthreads();

  const int rl  = lane & 15;
  const int krd = (lane >> 4) * 8;
  int cur = 0;
  constexpr int NK = D / BK;  // 32
#pragma unroll 2
  for (int kt = 0; kt < NK; ++kt) {
    if (kt + 1 < NK) LOAD((kt + 1) * BK);
    const u16* buf = lds[cur];
    short8 a[4], bg[2], bu[2];
#pragma unroll
    for (int mf = 0; mf < 4; ++mf)
      a[mf] = *reinterpret_cast<const short8*>(&buf[OX + (mf * 16 + rl) * KPAD + krd]);
#pragma unroll
    for (int nf = 0; nf < 2; ++nf) {
      const int r = wv * 32 + nf * 16 + rl;
      bg[nf] = *reinterpret_cast<const short8*>(&buf[OG + r * KPAD + krd]);
      bu[nf] = *reinterpret_cast<const short8*>(&buf[OU + r * KPAD + krd]);
    }
#pragma unroll
    for (int mf = 0; mf < 4; ++mf)
#pragma unroll
      for (int nf = 0; nf < 2; ++nf) {
        accg[mf][nf] = __builtin_amdgcn_mfma_f32_16x16x32_bf16(a[mf], bg[nf], accg[mf][nf], 0, 0, 0);
        accu[mf][nf] = __builtin_amdgcn_mfma_f32_16x16x32_bf16(a[mf], bu[nf], accu[mf][nf], 0, 0, 0);
      }
    if (kt + 1 < NK) STORE(lds[cur ^ 1]);
    __syncthreads();
    cur ^= 1;
  }

  // epilogue: silu(g)*u -> bf16 hidden. C/D layout: col=lane&15, row=(lane>>4)*4+reg
#pragma unroll
  for (int mf = 0; mf < 4; ++mf)
#pragma unroll
    for (int nf = 0; nf < 2; ++nf)
#pragma unroll
      for (int r = 0; r < 4; ++r) {
        float g = accg[mf][nf][r];
        float u = accu[mf][nf][r];
        float h = (g / (1.f + __expf(-g))) * u;
        int c = mf * 16 + (lane >> 4) * 4 + r;
        int f = n0 + wv * 32 + nf * 16 + rl;
        H[(size_t)(e * C + c) * DF + f] = f2bf(h);
      }
}

// ---------------- Stage 2: out = hidden * Wd^T (fp32 out) ------------------
__global__ __launch_bounds__(256, 2) void ffn_stage2(
    const u16* __restrict__ H, const float* __restrict__ Wd,
    float* __restrict__ out) {
  const int e   = blockIdx.y;
  const int n0  = blockIdx.x * BN;
  const int tid = threadIdx.x;
  const int lane = tid & 63;
  const int wv   = tid >> 6;

  __shared__ __align__(16) u16 lds[2][7680];  // A 64x40 | B 128x40
  constexpr int OA = 0, OB = 2560;

  const int arow = tid >> 2, as = (tid & 3) * 8;
  const int wrow = tid >> 1, wh = (tid & 1) * 16;

  const u16*   ap = H  + (size_t)(e * C + arow) * DF + as;
  const float* bp = Wd + ((size_t)e * D + n0 + wrow) * DF + wh;

  short8 av;
  float4v bv[4];

  auto LOAD = [&](int k0) {
    av = *reinterpret_cast<const short8*>(ap + k0);
    const float4v* b4 = reinterpret_cast<const float4v*>(bp + k0);
    bv[0] = b4[0]; bv[1] = b4[1]; bv[2] = b4[2]; bv[3] = b4[3];
  };
  auto STORE = [&](u16* buf) {
    *reinterpret_cast<short8*>(&buf[OA + arow * KPAD + as]) = av;
    short8 b0, b1;
#pragma unroll
    for (int i = 0; i < 4; ++i) {
      b0[i] = (short)f2bf(bv[0][i]); b0[4 + i] = (short)f2bf(bv[1][i]);
      b1[i] = (short)f2bf(bv[2][i]); b1[4 + i] = (short)f2bf(bv[3][i]);
    }
    u16* wb = &buf[OB + wrow * KPAD + wh];
    *reinterpret_cast<short8*>(wb)     = b0;
    *reinterpret_cast<short8*>(wb + 8) = b1;
  };

  const f32x4 zero = {0.f, 0.f, 0.f, 0.f};
  f32x4 acc[4][2];
#pragma unroll
  for (int mf = 0; mf < 4; ++mf)
#pragma unroll
    for (int nf = 0; nf < 2; ++nf) acc[mf][nf] = zero;

  LOAD(0);
  STORE(lds[0]);
  __syncthreads();

  const int rl  = lane & 15;
  const int krd = (lane >> 4) * 8;
  int cur = 0;
  constexpr int NK = DF / BK;  // 64
#pragma unroll 2
  for (int kt = 0; kt < NK; ++kt) {
    if (kt + 1 < NK) LOAD((kt + 1) * BK);
    const u16* buf = lds[cur];
    short8 a[4], b[2];
#pragma unroll
    for (int mf = 0; mf < 4; ++mf)
      a[mf] = *reinterpret_cast<const short8*>(&buf[OA + (mf * 16 + rl) * KPAD + krd]);
#pragma unroll
    for (int nf = 0; nf < 2; ++nf)
      b[nf] = *reinterpret_cast<const short8*>(&buf[OB + (wv * 32 + nf * 16 + rl) * KPAD + krd]);
#pragma unroll
    for (int mf = 0; mf < 4; ++mf)
#pragma unroll
      for (int nf = 0; nf < 2; ++nf)
        acc[mf][nf] = __builtin_amdgcn_mfma_f32_16x16x32_bf16(a[mf], b[nf], acc[mf][nf], 0, 0, 0);
    if (kt + 1 < NK) STORE(lds[cur ^ 1]);
    __syncthreads();
    cur ^= 1;
  }

#pragma unroll
  for (int mf = 0; mf < 4; ++mf)
#pragma unroll
    for (int nf = 0; nf < 2; ++nf)
#pragma unroll
      for (int r = 0; r < 4; ++r) {
        int c = mf * 16 + (lane >> 4) * 4 + r;
        int d = n0 + wv * 32 + nf * 16 + rl;
        out[(size_t)(e * C + c) * D + d] = acc[mf][nf][r];
      }
}

}  // namespace

extern "C" void kernel_launch(void* const* d_in, const int* in_sizes, int n_in,
                              void* d_out, int out_size, void* d_ws, size_t ws_size,
                              hipStream_t stream) {
  const float* X  = (const float*)d_in[0];
  const float* Wg = (const float*)d_in[1];
  const float* Wu = (const float*)d_in[2];
  const float* Wd = (const float*)d_in[3];
  float* out = (float*)d_out;
  u16* H = (u16*)d_ws;  // E*C*DF bf16 = 16.8 MB scratch

  ffn_stage1<<<dim3(DF / BN, E), dim3(256), 0, stream>>>(X, Wg, Wu, H);
  ffn_stage2<<<dim3(D / BN, E), dim3(256), 0, stream>>>(H, Wd, out);
}